// Round 11
// baseline (63.912 us; speedup 1.0000x reference)
//
#include <hip/hip_runtime.h>

// Quantized 3x3 conv, stride 1, pad 1 (pad value = input zero point 3).
// x: int32 [32][128][56][56] (values in int8 range)
// weight: int32 [256][128][3][3]
// bias: int32 [256]
// weight_scale: float [256]
// out: int32 [32][256][56][56] (quantized int8 values in int32 container)

#define NB    32
#define CIN   128
#define HH    56
#define WW    56
#define COUT  256
#define HP    58          // padded H
#define WP    58          // padded W
#define PIX   (HH*WW)     // 3136
#define KTOT  1152        // 9 * 128
#define NCHUNK 18         // K chunks of 64
#define NPHASE 9          // 2 chunks per phase

#define NPT   28          // pixel tiles per batch (3136 = 28*112)
#define BN    112         // pixels per block
#define NJ    7           // B fragments per wave (112/16)
#define CHB   (NJ*1024)   // one chunk of B in LDS: 7168 B
#define PHB   (2*CHB)     // one phase (2 chunks): 14336 B; ring of 3

typedef int v4i __attribute__((ext_vector_type(4)));

#define GLOAD_LDS(gsrc, ldst) \
    __builtin_amdgcn_global_load_lds( \
        (const __attribute__((address_space(1))) void*)(gsrc), \
        (__attribute__((address_space(3))) void*)(ldst), 16, 0, 0)

// ---------------- Phase 1a: pack x (NCHW int32 -> padded NHWC int8) -------
// LDS-transpose: coalesced global reads (lanes = w) AND coalesced global
// writes (lanes = contiguous dwords). LDS u32 tile [56][33] (2-way alias,
// free). Borders filled inline; all threads reach the barrier.
__global__ void pack_x_kernel(const int* __restrict__ x,
                              unsigned char* __restrict__ xp8,
                              int n0) {
    int bx = blockIdx.x;
    int nl = bx / HP;
    int hp = bx % HP;
    int nb = n0 + nl;
    int tid = threadIdx.x;         // 256
    unsigned int* rowo = (unsigned int*)(xp8 + (size_t)(nl*HP + hp) * WP * CIN);

    if (hp == 0 || hp == HP-1) {   // full pad row: 1856 dwords
        const v4i zp = {0x03030303, 0x03030303, 0x03030303, 0x03030303};
        for (int i = tid; i < (WP*CIN)/16; i += 256)
            ((v4i*)rowo)[i] = zp;
        return;
    }

    __shared__ unsigned int lt[WW * 33];   // 56 x 33 dwords = 7392 B

    int h  = hp - 1;
    int wl = tid & 63;             // lane = w (0..55 active)
    int cg = tid >> 6;             // wave index = ci phase 0..3
    if (wl < WW) {
        const int s = HH*WW;
#pragma unroll
        for (int k = 0; k < 8; ++k) {
            int ci0 = cg*4 + k*16;
            const int* xb = x + (((size_t)(nb*CIN + ci0)*HH + h)*WW + wl);
            int v0 = xb[0], v1 = xb[s], v2 = xb[2*s], v3 = xb[3*s];
            unsigned int pack = (v0 & 0xFF) | ((v1 & 0xFF) << 8) |
                                ((v2 & 0xFF) << 16) | ((unsigned)(v3 & 0xFF) << 24);
            lt[wl*33 + (ci0 >> 2)] = pack;
        }
    }
    __syncthreads();

#pragma unroll
    for (int it = 0; it < 7; ++it) {
        int idx = it*256 + tid;
        int p = idx >> 5;          // pixel 0..55
        int d = idx & 31;          // dword within pixel
        rowo[(p + 1)*32 + d] = lt[p*33 + d];
    }
    if (tid < 64) {
        int off = (tid < 32) ? tid : ((WP-1)*32 + (tid - 32));
        rowo[off] = 0x03030303u;
    }
}

// ---------------- Phase 1b: pack weight into FRAGMENT order ----------------
// w8f[((t*16 + g)*16 + lr)*64 + (k&63)], t=k>>6 chunk, g=co>>4, lr=co&15,
// k = r*128 + ci (tap-major). A wave's A-fragment = contiguous 1KB.
__global__ void pack_w_kernel(const int* __restrict__ wt,
                              unsigned char* __restrict__ w8f) {
    int co = blockIdx.x;           // 256
    int t  = threadIdx.x;          // 128
    for (int idx = t; idx < KTOT/4; idx += 128) {
        int k  = idx * 4;
        int r  = k >> 7;           // tap 0..8
        int ci = k & 127;
        const int* wb = wt + ((co*CIN + ci)*9 + r);
        int v0 = wb[0], v1 = wb[9], v2 = wb[18], v3 = wb[27];
        unsigned int pack = (v0 & 0xFF) | ((v1 & 0xFF) << 8) |
                            ((v2 & 0xFF) << 16) | ((unsigned)(v3 & 0xFF) << 24);
        int tch = k >> 6;
        size_t dst = ((size_t)((tch*16 + (co >> 4))*16 + (co & 15)))*64 + (k & 63);
        *(unsigned int*)(w8f + dst) = pack;
    }
}

__device__ __forceinline__ int koff_of(int t) {
    int r  = t >> 1;
    int kh = (r >= 6) ? 2 : (r >= 3 ? 1 : 0);
    int kw = r - kh*3;
    return ((kh*WP + kw) << 7) + ((t & 1) << 6);
}

// ---------------- Phase 2: ring-buffered 2-chunk-phase implicit GEMM ------
// Grid: 28 pixel-tiles * nc batches. Block: 256 threads = 4 waves.
// Tile: 256 co x 112 px. 9 phases of 2 K-chunks; ONE barrier per phase.
// B: LDS ring of 3 phase-buffers. vmcnt(12) = A(p-1)x8 + stage(p+1)x4.
// A: fragment-ordered w8f -> a[8] regs, loaded pre-barrier.
__launch_bounds__(256, 2)
__global__ void conv_kernel(const unsigned char* __restrict__ w8f,
                            const unsigned char* __restrict__ xp8,
                            const int* __restrict__ bias,
                            const float* __restrict__ wscale,
                            int* __restrict__ out,
                            int n0) {
    __shared__ __align__(16) unsigned char ldsB[3*PHB];

    int bx = blockIdx.x;
    int pt = bx % NPT;
    int nl = bx / NPT;
    int nb = n0 + nl;
    int p0 = pt * BN;

    int tid  = threadIdx.x;
    int lane = tid & 63;
    int wm   = tid >> 6;           // 0..3
    int lr   = lane & 15;
    int lg   = lane >> 4;

    // ---- B staging: slots s0,s1 per wave (16 px x 64B each) ----
    int l4 = lane >> 2;                              // row within 16-row group
    int sw = (lane & 3) ^ ((lane >> 3) & 3);         // swizzled data k-slot
    int s0 = wm*2;
    int s1 = (wm*2+1 > 6) ? 6 : wm*2+1;              // wave3 duplicates slot 6
    int s0u = __builtin_amdgcn_readfirstlane(s0);
    int s1u = __builtin_amdgcn_readfirstlane(s1);
    int pA = p0 + s0*16 + l4;
    int pB = p0 + s1*16 + l4;
    const unsigned char* bsrc0 =
        xp8 + ((size_t)((nl*HP + pA/WW)*WP + pA%WW))*CIN + sw*16;
    const unsigned char* bsrc1 =
        xp8 + ((size_t)((nl*HP + pB/WW)*WP + pB%WW))*CIN + sw*16;

    // ---- B fragment read address (swizzled) ----
    int rslot = lg ^ ((lr >> 1) & 3);
    int vb = lr*64 + rslot*16;                       // b[j] at vb + j*1024

    // ---- A fragment base: contiguous 1KB per (chunk, frag) ----
    const unsigned char* abase = w8f + (size_t)(wm*4)*1024 + (lr*64 + lg*16);

    v4i acc[4][NJ];
#pragma unroll
    for (int i = 0; i < 4; ++i)
#pragma unroll
        for (int j = 0; j < NJ; ++j)
            acc[i][j] = (v4i){0, 0, 0, 0};

#define STAGE2(P, ROFF) do {                                                   \
        int k0_ = koff_of(2*(P));                                              \
        int k1_ = koff_of(2*(P)+1);                                            \
        GLOAD_LDS(bsrc0 + k0_, &ldsB[(ROFF) + s0u*1024]);                      \
        GLOAD_LDS(bsrc1 + k0_, &ldsB[(ROFF) + s1u*1024]);                      \
        GLOAD_LDS(bsrc0 + k1_, &ldsB[(ROFF) + CHB + s0u*1024]);                \
        GLOAD_LDS(bsrc1 + k1_, &ldsB[(ROFF) + CHB + s1u*1024]);                \
    } while (0)

    // prologue: stage phase 0 into ring slot 0
    STAGE2(0, 0);

#pragma unroll
    for (int p = 0; p < NPHASE; ++p) {
        if (p < NPHASE-1) STAGE2(p+1, ((p+1)%3)*PHB);

        v4i a_[8];
#pragma unroll
        for (int i = 0; i < 4; ++i) {
            a_[i]   = *(const v4i*)(abase + (size_t)(2*p)*16384   + i*1024);
            a_[4+i] = *(const v4i*)(abase + (size_t)(2*p+1)*16384 + i*1024);
        }

        asm volatile("s_waitcnt vmcnt(12)" ::: "memory");
        __builtin_amdgcn_sched_barrier(0);
        __builtin_amdgcn_s_barrier();      // all waves' phase-p B in LDS

        int roff = (p % 3) * PHB;
        v4i b_[NJ];
#pragma unroll
        for (int j = 0; j < NJ; ++j)
            b_[j] = *(const v4i*)&ldsB[roff + vb + j*1024];
#pragma unroll
        for (int i = 0; i < 4; ++i)
#pragma unroll
            for (int j = 0; j < NJ; ++j)
                acc[i][j] = __builtin_amdgcn_mfma_i32_16x16x64_i8(
                    a_[i], b_[j], acc[i][j], 0, 0, 0);
#pragma unroll
        for (int j = 0; j < NJ; ++j)
            b_[j] = *(const v4i*)&ldsB[roff + CHB + vb + j*1024];
#pragma unroll
        for (int i = 0; i < 4; ++i)
#pragma unroll
            for (int j = 0; j < NJ; ++j)
                acc[i][j] = __builtin_amdgcn_mfma_i32_16x16x64_i8(
                    a_[4+i], b_[j], acc[i][j], 0, 0, 0);
    }
#undef STAGE2

    // Epilogue: q = clamp(rint((acc+bias) * (0.05*ws/0.1) + (-2)), -128, 127)
#pragma unroll
    for (int i = 0; i < 4; ++i) {
#pragma unroll
        for (int rr = 0; rr < 4; ++rr) {
            int co = wm*64 + i*16 + lg*4 + rr;
            float sc = __fdiv_rn(__fmul_rn(0.05f, wscale[co]), 0.1f);
            int bs = bias[co];
            int* orow = out + ((size_t)(nb*COUT + co))*PIX + p0;
#pragma unroll
            for (int j = 0; j < NJ; ++j) {
                float accf = (float)(acc[i][j][rr] + bs);
                float y = __fadd_rn(__fmul_rn(accf, sc), -2.0f);
                y = rintf(y);
                y = fminf(fmaxf(y, -128.0f), 127.0f);
                orow[j*16 + lr] = (int)y;
            }
        }
    }
}

// ---------------- Fallback: naive direct conv (only if ws too small) ------
__launch_bounds__(256)
__global__ void conv_direct_kernel(const int* __restrict__ x,
                                   const int* __restrict__ wt,
                                   const int* __restrict__ bias,
                                   const float* __restrict__ wscale,
                                   int* __restrict__ out) {
    size_t idx = (size_t)blockIdx.x * 256 + threadIdx.x;
    if (idx >= (size_t)NB * COUT * PIX) return;
    int w  = idx % WW;
    int h  = (idx / WW) % HH;
    int co = (idx / PIX) % COUT;
    int nb = idx / ((size_t)PIX * COUT);
    int acc = 0;
    for (int ci = 0; ci < CIN; ++ci) {
        const int* xb = x + ((size_t)(nb*CIN + ci)*HH)*WW;
        const int* wb = wt + ((size_t)(co*CIN + ci)*9);
        for (int kh = 0; kh < 3; ++kh) {
            int hh = h + kh - 1;
            for (int kw = 0; kw < 3; ++kw) {
                int ww2 = w + kw - 1;
                int xv = (hh >= 0 && hh < HH && ww2 >= 0 && ww2 < WW)
                         ? xb[hh*WW + ww2] : 3;
                acc += xv * wb[kh*3 + kw];
            }
        }
    }
    float sc = __fdiv_rn(__fmul_rn(0.05f, wscale[co]), 0.1f);
    float y = __fadd_rn(__fmul_rn((float)(acc + bias[co]), sc), -2.0f);
    y = rintf(y);
    y = fminf(fmaxf(y, -128.0f), 127.0f);
    out[idx] = (int)y;
}

extern "C" void kernel_launch(void* const* d_in, const int* in_sizes, int n_in,
                              void* d_out, int out_size, void* d_ws, size_t ws_size,
                              hipStream_t stream) {
    const int*   x      = (const int*)d_in[0];
    const int*   weight = (const int*)d_in[1];
    const int*   bias   = (const int*)d_in[2];
    const float* wscale = (const float*)d_in[3];
    int*         out    = (int*)d_out;

    const size_t XOFF = 320u << 10;                  // w8f region: 288KB used
    const size_t BPB  = (size_t)HP * WP * CIN;       // 430,592 B per batch
    const size_t SLAB = (size_t)COUT * PIX * 4;      // 3,211,264 B out per batch

    size_t navail = (ws_size > XOFF) ? (ws_size - XOFF) / BPB : 0;

    unsigned char* w8f = (unsigned char*)d_ws;
    unsigned char* xpw = (unsigned char*)d_ws + XOFF;

    if (navail >= 4) {
        // Two-pass d_out-scratch scheme:
        //  - wsN batches staged in d_ws, Na = 32-wsN batches staged in the
        //    TAIL of d_out (byte offset Na*SLAB = the region that only
        //    batches Na..31's output occupies).
        //  - conv_A (batches 0..Na-1) reads the tail, writes slabs 0..Na-1
        //    (disjoint from tail since Na <= 28: Na*BPB <= (32-Na)*SLAB).
        //  - conv_B (batches Na..31) reads d_ws, runs after conv_A, and
        //    overwrites the tail with its output. Every output byte written.
        int wsN = (int)(navail < 32 ? navail : 32);
        int Na  = 32 - wsN;        // 0..28
        unsigned char* xpt = (unsigned char*)d_out + (size_t)Na * SLAB;

        pack_w_kernel<<<dim3(COUT), dim3(128), 0, stream>>>(weight, w8f);
        if (Na > 0)
            pack_x_kernel<<<dim3(Na*HP), dim3(256), 0, stream>>>(x, xpt, 0);
        pack_x_kernel<<<dim3(wsN*HP), dim3(256), 0, stream>>>(x, xpw, Na);
        if (Na > 0)
            conv_kernel<<<dim3(NPT*Na), dim3(256), 0, stream>>>(
                w8f, xpt, bias, wscale, out, 0);
        conv_kernel<<<dim3(NPT*wsN), dim3(256), 0, stream>>>(
            w8f, xpw, bias, wscale, out, Na);
    } else if (navail >= 1) {
        // Old chunked scheme for tiny workspaces.
        int nchk = navail >= 2 ? 2 : 1;
        pack_w_kernel<<<dim3(COUT), dim3(128), 0, stream>>>(weight, w8f);
        for (int n0 = 0; n0 < NB; n0 += nchk) {
            int nc = (NB - n0 < nchk) ? (NB - n0) : nchk;
            pack_x_kernel<<<dim3(nc*HP), dim3(256), 0, stream>>>(x, xpw, n0);
            conv_kernel<<<dim3(NPT*nc), dim3(256), 0, stream>>>(
                w8f, xpw, bias, wscale, out, n0);
        }
    } else {
        size_t total = (size_t)NB * COUT * PIX;
        conv_direct_kernel<<<dim3((total + 255) / 256), dim3(256), 0, stream>>>(
            x, weight, bias, wscale, out);
    }
}

// Round 12
// 63.368 us; speedup vs baseline: 1.0086x; 1.0086x over previous
//
#include <hip/hip_runtime.h>

// Quantized 3x3 conv, stride 1, pad 1 (pad value = input zero point 3).
// x: int32 [32][128][56][56] (values in int8 range)
// weight: int32 [256][128][3][3]
// bias: int32 [256]
// weight_scale: float [256]
// out: int32 [32][256][56][56] (quantized int8 values in int32 container)

#define NB    32
#define CIN   128
#define HH    56
#define WW    56
#define COUT  256
#define HP    58          // padded H
#define WP    58          // padded W
#define PIX   (HH*WW)     // 3136
#define KTOT  1152        // 9 * 128
#define NCHUNK 18         // K chunks of 64
#define NPHASE 9          // 2 chunks per phase

#define NPT   28          // pixel tiles per batch (3136 = 28*112)
#define BN    112         // pixels per block
#define NJ    7           // B fragments per wave (112/16)
#define CHB   (NJ*1024)   // one chunk of B in LDS: 7168 B
#define PHB   (2*CHB)     // one phase (2 chunks): 14336 B; ring of 3

typedef int v4i __attribute__((ext_vector_type(4)));

#define GLOAD_LDS(gsrc, ldst) \
    __builtin_amdgcn_global_load_lds( \
        (const __attribute__((address_space(1))) void*)(gsrc), \
        (__attribute__((address_space(3))) void*)(ldst), 16, 0, 0)

// ---------------- Phase 1a: pack x (NCHW int32 -> padded NHWC int8) -------
// LDS-transpose: coalesced global reads (lanes = w) AND coalesced global
// writes (lanes = contiguous dwords). LDS u32 tile [56][33] (2-way alias,
// free). Borders filled inline; all threads reach the barrier.
__global__ void pack_x_kernel(const int* __restrict__ x,
                              unsigned char* __restrict__ xp8,
                              int n0) {
    int bx = blockIdx.x;
    int nl = bx / HP;
    int hp = bx % HP;
    int nb = n0 + nl;
    int tid = threadIdx.x;         // 256
    unsigned int* rowo = (unsigned int*)(xp8 + (size_t)(nl*HP + hp) * WP * CIN);

    if (hp == 0 || hp == HP-1) {   // full pad row: 1856 dwords
        const v4i zp = {0x03030303, 0x03030303, 0x03030303, 0x03030303};
        for (int i = tid; i < (WP*CIN)/16; i += 256)
            ((v4i*)rowo)[i] = zp;
        return;
    }

    __shared__ unsigned int lt[WW * 33];   // 56 x 33 dwords = 7392 B

    int h  = hp - 1;
    int wl = tid & 63;             // lane = w (0..55 active)
    int cg = tid >> 6;             // wave index = ci phase 0..3
    if (wl < WW) {
        const int s = HH*WW;
#pragma unroll
        for (int k = 0; k < 8; ++k) {
            int ci0 = cg*4 + k*16;
            const int* xb = x + (((size_t)(nb*CIN + ci0)*HH + h)*WW + wl);
            int v0 = xb[0], v1 = xb[s], v2 = xb[2*s], v3 = xb[3*s];
            unsigned int pack = (v0 & 0xFF) | ((v1 & 0xFF) << 8) |
                                ((v2 & 0xFF) << 16) | ((unsigned)(v3 & 0xFF) << 24);
            lt[wl*33 + (ci0 >> 2)] = pack;
        }
    }
    __syncthreads();

#pragma unroll
    for (int it = 0; it < 7; ++it) {
        int idx = it*256 + tid;
        int p = idx >> 5;          // pixel 0..55
        int d = idx & 31;          // dword within pixel
        rowo[(p + 1)*32 + d] = lt[p*33 + d];
    }
    if (tid < 64) {
        int off = (tid < 32) ? tid : ((WP-1)*32 + (tid - 32));
        rowo[off] = 0x03030303u;
    }
}

// ---------------- Phase 1b: pack weight into FRAGMENT order ----------------
// w8f[((t*16 + g)*16 + lr)*64 + (k&63)], t=k>>6 chunk, g=co>>4, lr=co&15,
// k = r*128 + ci (tap-major). A 16co-fragment = contiguous 1KB.
__global__ void pack_w_kernel(const int* __restrict__ wt,
                              unsigned char* __restrict__ w8f) {
    int co = blockIdx.x;           // 256
    int t  = threadIdx.x;          // 128
    for (int idx = t; idx < KTOT/4; idx += 128) {
        int k  = idx * 4;
        int r  = k >> 7;           // tap 0..8
        int ci = k & 127;
        const int* wb = wt + ((co*CIN + ci)*9 + r);
        int v0 = wb[0], v1 = wb[9], v2 = wb[18], v3 = wb[27];
        unsigned int pack = (v0 & 0xFF) | ((v1 & 0xFF) << 8) |
                            ((v2 & 0xFF) << 16) | ((unsigned)(v3 & 0xFF) << 24);
        int tch = k >> 6;
        size_t dst = ((size_t)((tch*16 + (co >> 4))*16 + (co & 15)))*64 + (k & 63);
        *(unsigned int*)(w8f + dst) = pack;
    }
}

__device__ __forceinline__ int koff_of(int t) {
    int r  = t >> 1;
    int kh = (r >= 6) ? 2 : (r >= 3 ? 1 : 0);
    int kw = r - kh*3;
    return ((kh*WP + kw) << 7) + ((t & 1) << 6);
}

// ---------------- Phase 2: high-occupancy ring-buffered implicit GEMM -----
// Grid: 2 co-halves * 28 pixel-tiles * nc batches. Block: 256 thr = 4 waves.
// Tile: 128co x 112px; wave wm owns co [ch*128+wm*32, +32) x 112px.
// acc[2][7] = 56 AGPR -> ~140 regs/wave -> 3 waves/SIMD, 3 blocks/CU
// (LDS ring 43KB). 9 phases of 2 K-chunks, ONE barrier per phase.
// vmcnt(8) = this-iter issue count (4 stage + 4 A): sound guarantee that
// stage(p) (and all older) retired before the barrier.
__launch_bounds__(256, 3)
__global__ void conv_kernel(const unsigned char* __restrict__ w8f,
                            const unsigned char* __restrict__ xp8,
                            const int* __restrict__ bias,
                            const float* __restrict__ wscale,
                            int* __restrict__ out,
                            int n0) {
    __shared__ __align__(16) unsigned char ldsB[3*PHB];

    int bx = blockIdx.x;
    int ch = bx & 1;               // co-half (fastest-varying: pair shares B)
    int bxr = bx >> 1;
    int pt = bxr % NPT;
    int nl = bxr / NPT;
    int nb = n0 + nl;
    int p0 = pt * BN;

    int tid  = threadIdx.x;
    int lane = tid & 63;
    int wm   = tid >> 6;           // 0..3
    int lr   = lane & 15;
    int lg   = lane >> 4;

    // ---- B staging: slots s0,s1 per wave (16 px x 64B each) ----
    int l4 = lane >> 2;                              // row within 16-row group
    int sw = (lane & 3) ^ ((lane >> 3) & 3);         // swizzled data k-slot
    int s0 = wm*2;
    int s1 = (wm*2+1 > 6) ? 6 : wm*2+1;              // wave3 duplicates slot 6
    int s0u = __builtin_amdgcn_readfirstlane(s0);
    int s1u = __builtin_amdgcn_readfirstlane(s1);
    int pA = p0 + s0*16 + l4;
    int pB = p0 + s1*16 + l4;
    const unsigned char* bsrc0 =
        xp8 + ((size_t)((nl*HP + pA/WW)*WP + pA%WW))*CIN + sw*16;
    const unsigned char* bsrc1 =
        xp8 + ((size_t)((nl*HP + pB/WW)*WP + pB%WW))*CIN + sw*16;

    // ---- B fragment read address (swizzled) ----
    int rslot = lg ^ ((lr >> 1) & 3);
    int vb = lr*64 + rslot*16;                       // b[j] at vb + j*1024

    // ---- A fragment base: frag g = ch*8 + wm*2 + i (i=0,1), 1KB each ----
    const unsigned char* abase =
        w8f + (size_t)(ch*8 + wm*2)*1024 + (lr*64 + lg*16);

    v4i acc[2][NJ];
#pragma unroll
    for (int i = 0; i < 2; ++i)
#pragma unroll
        for (int j = 0; j < NJ; ++j)
            acc[i][j] = (v4i){0, 0, 0, 0};

#define STAGE2(P, ROFF) do {                                                   \
        int k0_ = koff_of(2*(P));                                              \
        int k1_ = koff_of(2*(P)+1);                                            \
        GLOAD_LDS(bsrc0 + k0_, &ldsB[(ROFF) + s0u*1024]);                      \
        GLOAD_LDS(bsrc1 + k0_, &ldsB[(ROFF) + s1u*1024]);                      \
        GLOAD_LDS(bsrc0 + k1_, &ldsB[(ROFF) + CHB + s0u*1024]);                \
        GLOAD_LDS(bsrc1 + k1_, &ldsB[(ROFF) + CHB + s1u*1024]);                \
    } while (0)

    // prologue: stage phase 0 into ring slot 0
    STAGE2(0, 0);

#pragma unroll
    for (int p = 0; p < NPHASE; ++p) {
        if (p < NPHASE-1) STAGE2(p+1, ((p+1)%3)*PHB);

        v4i a_[4];                 // [i] chunk 2p, [2+i] chunk 2p+1
#pragma unroll
        for (int i = 0; i < 2; ++i) {
            a_[i]   = *(const v4i*)(abase + (size_t)(2*p)*16384   + i*1024);
            a_[2+i] = *(const v4i*)(abase + (size_t)(2*p+1)*16384 + i*1024);
        }

        if (p < NPHASE-1) {
            asm volatile("s_waitcnt vmcnt(8)" ::: "memory");
        } else {
            asm volatile("s_waitcnt vmcnt(4)" ::: "memory");
        }
        __builtin_amdgcn_sched_barrier(0);
        __builtin_amdgcn_s_barrier();      // all waves' phase-p B in LDS

        int roff = (p % 3) * PHB;
        v4i b_[NJ];
#pragma unroll
        for (int j = 0; j < NJ; ++j)
            b_[j] = *(const v4i*)&ldsB[roff + vb + j*1024];
#pragma unroll
        for (int i = 0; i < 2; ++i)
#pragma unroll
            for (int j = 0; j < NJ; ++j)
                acc[i][j] = __builtin_amdgcn_mfma_i32_16x16x64_i8(
                    a_[i], b_[j], acc[i][j], 0, 0, 0);
#pragma unroll
        for (int j = 0; j < NJ; ++j)
            b_[j] = *(const v4i*)&ldsB[roff + CHB + vb + j*1024];
#pragma unroll
        for (int i = 0; i < 2; ++i)
#pragma unroll
            for (int j = 0; j < NJ; ++j)
                acc[i][j] = __builtin_amdgcn_mfma_i32_16x16x64_i8(
                    a_[2+i], b_[j], acc[i][j], 0, 0, 0);
    }
#undef STAGE2

    // Epilogue: q = clamp(rint((acc+bias) * (0.05*ws/0.1) + (-2)), -128, 127)
#pragma unroll
    for (int i = 0; i < 2; ++i) {
#pragma unroll
        for (int rr = 0; rr < 4; ++rr) {
            int co = ch*128 + wm*32 + i*16 + lg*4 + rr;
            float sc = __fdiv_rn(__fmul_rn(0.05f, wscale[co]), 0.1f);
            int bs = bias[co];
            int* orow = out + ((size_t)(nb*COUT + co))*PIX + p0;
#pragma unroll
            for (int j = 0; j < NJ; ++j) {
                float accf = (float)(acc[i][j][rr] + bs);
                float y = __fadd_rn(__fmul_rn(accf, sc), -2.0f);
                y = rintf(y);
                y = fminf(fmaxf(y, -128.0f), 127.0f);
                orow[j*16 + lr] = (int)y;
            }
        }
    }
}

// ---------------- Fallback: naive direct conv (only if ws too small) ------
__launch_bounds__(256)
__global__ void conv_direct_kernel(const int* __restrict__ x,
                                   const int* __restrict__ wt,
                                   const int* __restrict__ bias,
                                   const float* __restrict__ wscale,
                                   int* __restrict__ out) {
    size_t idx = (size_t)blockIdx.x * 256 + threadIdx.x;
    if (idx >= (size_t)NB * COUT * PIX) return;
    int w  = idx % WW;
    int h  = (idx / WW) % HH;
    int co = (idx / PIX) % COUT;
    int nb = idx / ((size_t)PIX * COUT);
    int acc = 0;
    for (int ci = 0; ci < CIN; ++ci) {
        const int* xb = x + ((size_t)(nb*CIN + ci)*HH)*WW;
        const int* wb = wt + ((size_t)(co*CIN + ci)*9);
        for (int kh = 0; kh < 3; ++kh) {
            int hh = h + kh - 1;
            for (int kw = 0; kw < 3; ++kw) {
                int ww2 = w + kw - 1;
                int xv = (hh >= 0 && hh < HH && ww2 >= 0 && ww2 < WW)
                         ? xb[hh*WW + ww2] : 3;
                acc += xv * wb[kh*3 + kw];
            }
        }
    }
    float sc = __fdiv_rn(__fmul_rn(0.05f, wscale[co]), 0.1f);
    float y = __fadd_rn(__fmul_rn((float)(acc + bias[co]), sc), -2.0f);
    y = rintf(y);
    y = fminf(fmaxf(y, -128.0f), 127.0f);
    out[idx] = (int)y;
}

extern "C" void kernel_launch(void* const* d_in, const int* in_sizes, int n_in,
                              void* d_out, int out_size, void* d_ws, size_t ws_size,
                              hipStream_t stream) {
    const int*   x      = (const int*)d_in[0];
    const int*   weight = (const int*)d_in[1];
    const int*   bias   = (const int*)d_in[2];
    const float* wscale = (const float*)d_in[3];
    int*         out    = (int*)d_out;

    const size_t XOFF = 320u << 10;                  // w8f region: 288KB used
    const size_t BPB  = (size_t)HP * WP * CIN;       // 430,592 B per batch
    const size_t SLAB = (size_t)COUT * PIX * 4;      // 3,211,264 B out per batch

    size_t navail = (ws_size > XOFF) ? (ws_size - XOFF) / BPB : 0;

    unsigned char* w8f = (unsigned char*)d_ws;
    unsigned char* xpw = (unsigned char*)d_ws + XOFF;

    if (navail >= 4) {
        // Two-pass d_out-scratch scheme: Na batches staged in d_out's tail,
        // wsN batches in d_ws. conv_A writes slabs 0..Na-1 (disjoint from
        // tail); conv_B then overwrites the tail with its own output.
        int wsN = (int)(navail < 32 ? navail : 32);
        int Na  = 32 - wsN;        // 0..28
        unsigned char* xpt = (unsigned char*)d_out + (size_t)Na * SLAB;

        pack_w_kernel<<<dim3(COUT), dim3(128), 0, stream>>>(weight, w8f);
        if (Na > 0)
            pack_x_kernel<<<dim3(Na*HP), dim3(256), 0, stream>>>(x, xpt, 0);
        pack_x_kernel<<<dim3(wsN*HP), dim3(256), 0, stream>>>(x, xpw, Na);
        if (Na > 0)
            conv_kernel<<<dim3(2*NPT*Na), dim3(256), 0, stream>>>(
                w8f, xpt, bias, wscale, out, 0);
        conv_kernel<<<dim3(2*NPT*wsN), dim3(256), 0, stream>>>(
            w8f, xpw, bias, wscale, out, Na);
    } else if (navail >= 1) {
        // Old chunked scheme for tiny workspaces.
        int nchk = navail >= 2 ? 2 : 1;
        pack_w_kernel<<<dim3(COUT), dim3(128), 0, stream>>>(weight, w8f);
        for (int n0 = 0; n0 < NB; n0 += nchk) {
            int nc = (NB - n0 < nchk) ? (NB - n0) : nchk;
            pack_x_kernel<<<dim3(nc*HP), dim3(256), 0, stream>>>(x, xpw, n0);
            conv_kernel<<<dim3(2*NPT*nc), dim3(256), 0, stream>>>(
                w8f, xpw, bias, wscale, out, n0);
        }
    } else {
        size_t total = (size_t)NB * COUT * PIX;
        conv_direct_kernel<<<dim3((total + 255) / 256), dim3(256), 0, stream>>>(
            x, weight, bias, wscale, out);
    }
}